// Round 7
// baseline (696.314 us; speedup 1.0000x reference)
//
#include <hip/hip_runtime.h>
#include <hip/hip_bf16.h>

// EncoderLayer: B=4, L=2048, D=1024, H=16, dk=64, FF=4096.
//
// Round 6: A-direct GEMM. Round-6 post-mortem showed the GEMMs are
// LDS-read-bound (FF2: MfmaUtil 27% == MFMA-roofline share; 64x64 wave tile
// = 32 FLOP/LDS-byte < 46 needed). Fix: stream A-fragments straight from
// global (MFMA A-layout == row-major 16B/lane read), software-pipelined one
// K-iter ahead in registers; only B staged in LDS (8 KB, XOR-swizzled,
// global_load_lds). Halves LDS reads, puts A on the idle VMEM/L2 path.
// All GEMMs TM=128 (64x64 per wave).
//
// Workspace (136 MiB):
//   [0,16M) Qb | [16,32M) Kb | [32,48M) Vtb | [48,64M) CTXb
//   FFb=[0,64M) reuses after O-proj; Xf fp32 [64,96M); X1b [96,112M)
//   SRCb [112,128M) -> W1t [112,120M), W2t [120,128M) after QKV
//   Wqkvt [128,134M), Wot [134,136M)

#define D_MODEL 1024
#define SEQ     2048
#define BATCH   4
#define NHEAD   16
#define D_FF    4096
#define M_ROWS  (BATCH * SEQ)   // 8192

typedef __attribute__((ext_vector_type(8))) short bf16x8;
typedef __attribute__((ext_vector_type(4))) float f32x4;

__device__ __forceinline__ ushort f2bf(float x) {
    unsigned u = __float_as_uint(x);
    unsigned r = (u + 0x7FFFu + ((u >> 16) & 1u)) >> 16;   // RNE
    return (ushort)r;
}

// physical ushort offset of logical (row r, k-chunk q) in the swizzled tile
__device__ __forceinline__ int swz_off(int r, int q) {
    return ((r >> 1) << 6) | (((((r & 1) << 2) | q) ^ ((r >> 1) & 7)) << 3);
}

// ---------------------------------------------------------------------------
__global__ __launch_bounds__(256) void cast_kernel(
    const float* __restrict__ x, ushort* __restrict__ y)
{
    const size_t i = ((size_t)blockIdx.x * 256 + threadIdx.x) * 4;
    float4 v = *(const float4*)&x[i];
    ushort4 o;
    o.x = f2bf(v.x); o.y = f2bf(v.y); o.z = f2bf(v.z); o.w = f2bf(v.w);
    *(ushort4*)&y[i] = o;
}

// ---------------------------------------------------------------------------
// Generic W [R,C] fp32 -> Wt [C,R] bf16. grid = (C/64, R/64)
// ---------------------------------------------------------------------------
__global__ __launch_bounds__(256) void transpose_cast_kernel(
    const float* __restrict__ W, ushort* __restrict__ Wt, int R, int C)
{
    __shared__ float tile[64][68];
    const int c0 = blockIdx.x * 64, r0 = blockIdx.y * 64;
    const int t  = threadIdx.x;
    const int tc  = (t & 15) * 4;
    const int tr4 = (t >> 4) * 4;
#pragma unroll
    for (int i = 0; i < 4; ++i) {
        float4 v = *(const float4*)&W[(size_t)(r0 + tr4 + i) * C + c0 + tc];
        *(float4*)&tile[tr4 + i][tc] = v;
    }
    __syncthreads();
#pragma unroll
    for (int i = 0; i < 4; ++i) {
        const int nn = tr4 + i;
        ushort4 o;
        o.x = f2bf(tile[tc + 0][nn]);
        o.y = f2bf(tile[tc + 1][nn]);
        o.z = f2bf(tile[tc + 2][nn]);
        o.w = f2bf(tile[tc + 3][nn]);
        *(ushort4*)&Wt[(size_t)(c0 + nn) * R + r0 + tc] = o;
    }
}

// ---------------------------------------------------------------------------
// 4-in-1 1024x1024 transpose: z selects Wq/Wk/Wv (-> Wqkvt rows z*1024..) or
// Wo (-> Wot). grid = (16,16,4)
// ---------------------------------------------------------------------------
__global__ __launch_bounds__(256) void transpose_cast4_kernel(
    const float* __restrict__ Wq, const float* __restrict__ Wk,
    const float* __restrict__ Wv, const float* __restrict__ Wo,
    ushort* __restrict__ Wqkvt, ushort* __restrict__ Wot)
{
    const int z = blockIdx.z;
    const float* W = (z == 0) ? Wq : (z == 1) ? Wk : (z == 2) ? Wv : Wo;
    ushort* out = (z < 3) ? (Wqkvt + (size_t)z * 1024 * 1024) : Wot;

    __shared__ float tile[64][68];
    const int c0 = blockIdx.x * 64, r0 = blockIdx.y * 64;
    const int t  = threadIdx.x;
    const int tc  = (t & 15) * 4;
    const int tr4 = (t >> 4) * 4;
#pragma unroll
    for (int i = 0; i < 4; ++i) {
        float4 v = *(const float4*)&W[(size_t)(r0 + tr4 + i) * 1024 + c0 + tc];
        *(float4*)&tile[tr4 + i][tc] = v;
    }
    __syncthreads();
#pragma unroll
    for (int i = 0; i < 4; ++i) {
        const int nn = tr4 + i;
        ushort4 o;
        o.x = f2bf(tile[tc + 0][nn]);
        o.y = f2bf(tile[tc + 1][nn]);
        o.z = f2bf(tile[tc + 2][nn]);
        o.w = f2bf(tile[tc + 3][nn]);
        *(ushort4*)&out[(size_t)(c0 + nn) * 1024 + r0 + tc] = o;
    }
}

// ---------------------------------------------------------------------------
// bf16 MFMA GEMM, A-direct: C[M,N] = A[M,K] @ Bt[N,K]^T + bias.
// 128x128 tile, BK=32. A-fragments read straight from global (row-major,
// 16 B/lane, pipelined one iter ahead); B staged in LDS (XOR swizzle).
// XCD swizzle: bid&7 owns a contiguous row strip.
// MODE 0: fp32 [M,N]
// MODE 2: ReLU bf16 [M,N]
// MODE 4: fused QKV epilogue — col third 0: Q bf16 [B,H,L,64] scaled 1/8;
//         third 1: K bf16 [B,H,L,64]; third 2: V bf16 transposed [B,H,64,L].
// ---------------------------------------------------------------------------
template <int MODE>
__global__ __launch_bounds__(256) void gemm_mfma(
    const ushort* __restrict__ A, const ushort* __restrict__ Bt,
    const float* __restrict__ bias0, const float* __restrict__ bias1,
    const float* __restrict__ bias2, void* __restrict__ C,
    int M, int N, int K, int nx)
{
    __shared__ __attribute__((aligned(16))) ushort Bs[128 * 32];

    const int t    = threadIdx.x;
    const int lane = t & 63;
    const int wave = t >> 6;

    const int bid = blockIdx.y * gridDim.x + blockIdx.x;
    const int idx = bid >> 3;
    const int bxs = idx % nx;
    const int bys = (bid & 7) * (gridDim.y >> 3) + idx / nx;
    const int bm  = bys * 128;
    const int bn  = bxs * 128;

    const int wm   = (wave & 1) * 64;
    const int wn   = (wave >> 1) * 64;
    const int fr   = lane & 15;
    const int quad = lane >> 4;

    f32x4 acc[4][4];
#pragma unroll
    for (int i = 0; i < 4; ++i)
#pragma unroll
        for (int j = 0; j < 4; ++j)
            acc[i][j] = (f32x4){0.f, 0.f, 0.f, 0.f};

    // A-fragment base: row bm+wm+i*16+fr, cols quad*8..quad*8+7
    const ushort* Ap = A + (size_t)(bm + wm + fr) * K + quad * 8;

    bf16x8 afn[4];
#pragma unroll
    for (int i = 0; i < 4; ++i)
        afn[i] = *(const bf16x8*)(Ap + (size_t)(i * 16) * K);

    for (int k0 = 0; k0 < K; k0 += 32) {
        // stage B tile (swizzled DMA)
#pragma unroll
        for (int r = 0; r < 2; ++r) {
            const int s   = r * 256 + t;
            const int c   = (s & ~7) | ((s & 7) ^ ((s >> 3) & 7));
            const int row = c >> 2;
            const int kc  = (c & 3) * 8;
            __builtin_amdgcn_global_load_lds(
                (const __attribute__((address_space(1))) void*)(Bt + (size_t)(bn + row) * K + k0 + kc),
                (__attribute__((address_space(3))) void*)(Bs + s * 8), 16, 0, 0);
        }

        bf16x8 af[4];
#pragma unroll
        for (int i = 0; i < 4; ++i) af[i] = afn[i];
        const int kn = k0 + 32;
        if (kn < K) {
#pragma unroll
            for (int i = 0; i < 4; ++i)
                afn[i] = *(const bf16x8*)(Ap + (size_t)(i * 16) * K + kn);
        }

        __syncthreads();

        bf16x8 bfr[4];
#pragma unroll
        for (int j = 0; j < 4; ++j)
            bfr[j] = *(const bf16x8*)&Bs[swz_off(wn + j * 16 + fr, quad)];

#pragma unroll
        for (int i = 0; i < 4; ++i)
#pragma unroll
            for (int j = 0; j < 4; ++j)
                acc[i][j] = __builtin_amdgcn_mfma_f32_16x16x32_bf16(af[i], bfr[j], acc[i][j], 0, 0, 0);
        __syncthreads();
    }

    const int rbase = quad * 4;
#pragma unroll
    for (int j = 0; j < 4; ++j) {
        const int col   = bn + wn + j * 16 + fr;
        const int third = (bn + wn + j * 16) >> 10;         // wave-uniform
        float bc;
        float sc = 1.f;
        if (MODE == 4) {
            const float* bp = (third == 0) ? bias0 : (third == 1) ? bias1 : bias2;
            bc = bp[col & 1023];
            if (third == 0) sc = 0.125f;
        } else {
            bc = bias0[col];
        }
#pragma unroll
        for (int i = 0; i < 4; ++i) {
            const int row0 = bm + wm + i * 16 + rbase;
            float v[4];
#pragma unroll
            for (int r = 0; r < 4; ++r) v[r] = (acc[i][j][r] + bc) * sc;

            if (MODE == 0) {
#pragma unroll
                for (int r = 0; r < 4; ++r)
                    ((float*)C)[(size_t)(row0 + r) * N + col] = v[r];
            } else if (MODE == 2) {
#pragma unroll
                for (int r = 0; r < 4; ++r)
                    ((ushort*)C)[(size_t)(row0 + r) * N + col] = f2bf(fmaxf(v[r], 0.f));
            } else {  // MODE 4
                const int lc = col & 1023;
                const int h  = lc >> 6, d = lc & 63;
                if (third < 2) {
                    ushort* base = (ushort*)C + (size_t)third * 8 * 1024 * 1024;
#pragma unroll
                    for (int r = 0; r < 4; ++r) {
                        const int row = row0 + r;
                        const int b = row >> 11, l = row & 2047;
                        base[(((size_t)(b * NHEAD + h) * SEQ + l) << 6) + d] = f2bf(v[r]);
                    }
                } else {
                    ushort* base = (ushort*)C + (size_t)16 * 1024 * 1024;
                    const int b = row0 >> 11, l0 = row0 & 2047;
                    ushort4 o;
                    o.x = f2bf(v[0]); o.y = f2bf(v[1]); o.z = f2bf(v[2]); o.w = f2bf(v[3]);
                    *(ushort4*)&base[(((size_t)(b * NHEAD + h) * 64 + d) << 11) + l0] = o;
                }
            }
        }
    }
}

// ---------------------------------------------------------------------------
// MFMA flash attention (round-4 kernel, unchanged).
// ---------------------------------------------------------------------------
__global__ __launch_bounds__(256, 3) void attn_mfma(
    const ushort* __restrict__ Q, const ushort* __restrict__ K,
    const ushort* __restrict__ Vt, ushort* __restrict__ CTX)
{
    __shared__ __attribute__((aligned(16))) ushort Ks[64 * 64];
    __shared__ __attribute__((aligned(16))) ushort Vs[64 * 64];
    __shared__ __attribute__((aligned(16))) ushort Ps[128 * 64];

    const int t    = threadIdx.x;
    const int lane = t & 63;
    const int w    = t >> 6;
    const int l15  = lane & 15;
    const int quad = lane >> 4;

    const int bid = blockIdx.y * gridDim.x + blockIdx.x;
    const int idx = bid >> 3;
    const int bh  = (bid & 7) * 8 + (idx >> 4);
    const int q0  = (idx & 15) * 128;

    bf16x8 afq[2][2];
    const ushort* Qbase = Q + ((size_t)bh * SEQ + q0 + w * 32) * 64;
#pragma unroll
    for (int i = 0; i < 2; ++i)
#pragma unroll
        for (int ks = 0; ks < 2; ++ks)
            afq[i][ks] = *(const bf16x8*)&Qbase[(i * 16 + l15) * 64 + quad * 8 + ks * 32];

    f32x4 oacc[2][4];
#pragma unroll
    for (int i = 0; i < 2; ++i)
#pragma unroll
        for (int d = 0; d < 4; ++d) oacc[i][d] = (f32x4){0.f, 0.f, 0.f, 0.f};
    float lrun[2][4];
#pragma unroll
    for (int i = 0; i < 2; ++i)
#pragma unroll
        for (int r = 0; r < 4; ++r) lrun[i][r] = 0.f;

    const ushort* Kb  = K  + ((size_t)bh * SEQ) * 64;
    const ushort* Vtb = Vt + ((size_t)bh * 64) * SEQ;

    const int srow0 = t >> 3;          // 0..31
    const int sc8   = t & 7;           // chunk 0..7

    for (int kk0 = 0; kk0 < SEQ; kk0 += 64) {
        bf16x8 kv0 = *(const bf16x8*)&Kb[(size_t)(kk0 + srow0) * 64 + sc8 * 8];
        bf16x8 kv1 = *(const bf16x8*)&Kb[(size_t)(kk0 + srow0 + 32) * 64 + sc8 * 8];
        bf16x8 vv0 = *(const bf16x8*)&Vtb[(size_t)srow0 * SEQ + kk0 + sc8 * 8];
        bf16x8 vv1 = *(const bf16x8*)&Vtb[(size_t)(srow0 + 32) * SEQ + kk0 + sc8 * 8];

        __syncthreads();

        {
            const int pr0 = (srow0 & 3) * 16 + (srow0 >> 2);
            const int pr1 = ((srow0 + 32) & 3) * 16 + ((srow0 + 32) >> 2);
            *(bf16x8*)&Ks[pr0 * 64 + ((sc8 ^ (pr0 & 7)) << 3)] = kv0;
            *(bf16x8*)&Ks[pr1 * 64 + ((sc8 ^ (pr1 & 7)) << 3)] = kv1;
            *(bf16x8*)&Vs[srow0 * 64 + ((sc8 ^ (srow0 & 7)) << 3)] = vv0;
            *(bf16x8*)&Vs[(srow0 + 32) * 64 + ((sc8 ^ ((srow0 + 32) & 7)) << 3)] = vv1;
        }
        __syncthreads();

        f32x4 sacc[2][4];
#pragma unroll
        for (int i = 0; i < 2; ++i)
#pragma unroll
            for (int j = 0; j < 4; ++j) sacc[i][j] = (f32x4){0.f, 0.f, 0.f, 0.f};
        const int swz0 = (quad ^ (l15 & 7)) << 3;
        const int swz1 = ((quad + 4) ^ (l15 & 7)) << 3;
#pragma unroll
        for (int j = 0; j < 4; ++j) {
            const int krow = (j * 16 + l15) * 64;
            bf16x8 bk0 = *(const bf16x8*)&Ks[krow + swz0];
            bf16x8 bk1 = *(const bf16x8*)&Ks[krow + swz1];
            sacc[0][j] = __builtin_amdgcn_mfma_f32_16x16x32_bf16(afq[0][0], bk0, sacc[0][j], 0, 0, 0);
            sacc[0][j] = __builtin_amdgcn_mfma_f32_16x16x32_bf16(afq[0][1], bk1, sacc[0][j], 0, 0, 0);
            sacc[1][j] = __builtin_amdgcn_mfma_f32_16x16x32_bf16(afq[1][0], bk0, sacc[1][j], 0, 0, 0);
            sacc[1][j] = __builtin_amdgcn_mfma_f32_16x16x32_bf16(afq[1][1], bk1, sacc[1][j], 0, 0, 0);
        }

#pragma unroll
        for (int i = 0; i < 2; ++i) {
#pragma unroll
            for (int r = 0; r < 4; ++r) {
                const float p0 = __expf(sacc[i][0][r]);
                const float p1 = __expf(sacc[i][1][r]);
                const float p2 = __expf(sacc[i][2][r]);
                const float p3 = __expf(sacc[i][3][r]);
                lrun[i][r] += (p0 + p1) + (p2 + p3);
                const unsigned u0 = __builtin_amdgcn_perm(
                    __float_as_uint(p1), __float_as_uint(p0), 0x07060302u);
                const unsigned u1 = __builtin_amdgcn_perm(
                    __float_as_uint(p3), __float_as_uint(p2), 0x07060302u);
                const int prow = w * 32 + i * 16 + quad * 4 + r;
                const int off = prow * 64 + (((l15 >> 1) ^ (prow & 7)) << 3) + (l15 & 1) * 4;
                *(unsigned long long*)&Ps[off] =
                    (unsigned long long)u0 | ((unsigned long long)u1 << 32);
            }
        }

        bf16x8 ap[2][2];
#pragma unroll
        for (int i = 0; i < 2; ++i) {
            const int prow = (w * 32 + i * 16 + l15) * 64;
            ap[i][0] = *(const bf16x8*)&Ps[prow + swz0];
            ap[i][1] = *(const bf16x8*)&Ps[prow + swz1];
        }
#pragma unroll
        for (int dt = 0; dt < 4; ++dt) {
            const int vrow = (dt * 16 + l15) * 64;
            bf16x8 bv0 = *(const bf16x8*)&Vs[vrow + swz0];
            bf16x8 bv1 = *(const bf16x8*)&Vs[vrow + swz1];
            oacc[0][dt] = __builtin_amdgcn_mfma_f32_16x16x32_bf16(ap[0][0], bv0, oacc[0][dt], 0, 0, 0);
            oacc[0][dt] = __builtin_amdgcn_mfma_f32_16x16x32_bf16(ap[0][1], bv1, oacc[0][dt], 0, 0, 0);
            oacc[1][dt] = __builtin_amdgcn_mfma_f32_16x16x32_bf16(ap[1][0], bv0, oacc[1][dt], 0, 0, 0);
            oacc[1][dt] = __builtin_amdgcn_mfma_f32_16x16x32_bf16(ap[1][1], bv1, oacc[1][dt], 0, 0, 0);
        }
    }

    const int b = bh >> 4, h = bh & 15;
#pragma unroll
    for (int i = 0; i < 2; ++i) {
#pragma unroll
        for (int r = 0; r < 4; ++r) {
            float l = lrun[i][r];
#pragma unroll
            for (int m = 1; m < 16; m <<= 1) l += __shfl_xor(l, m, 64);
            const float inv = 1.f / l;
            const int tok = q0 + w * 32 + i * 16 + quad * 4 + r;
            ushort* op = CTX + ((size_t)(b * SEQ + tok)) * D_MODEL + h * 64;
#pragma unroll
            for (int dt = 0; dt < 4; ++dt)
                op[dt * 16 + l15] = f2bf(oacc[i][dt][r] * inv);
        }
    }
}

// ---------------------------------------------------------------------------
template <bool WRITE_BF>
__global__ __launch_bounds__(256) void ln_kernel(
    const float* __restrict__ y, const float* __restrict__ res,
    const float* __restrict__ g, const float* __restrict__ bta,
    float* __restrict__ out, ushort* __restrict__ out_bf)
{
    __shared__ float red[4];
    const int t = threadIdx.x;
    const size_t base = (size_t)blockIdx.x * D_MODEL + t * 4;

    float4 a = *(const float4*)&y[base];
    float4 r = *(const float4*)&res[base];
    const float v0 = a.x + r.x, v1 = a.y + r.y, v2 = a.z + r.z, v3 = a.w + r.w;

    float s = v0 + v1 + v2 + v3;
#pragma unroll
    for (int o = 32; o > 0; o >>= 1) s += __shfl_down(s, o, 64);
    if ((t & 63) == 0) red[t >> 6] = s;
    __syncthreads();
    const float mu = (red[0] + red[1] + red[2] + red[3]) * (1.f / 1024.f);

    const float d0 = v0 - mu, d1 = v1 - mu, d2 = v2 - mu, d3 = v3 - mu;
    float sq = d0 * d0 + d1 * d1 + d2 * d2 + d3 * d3;
#pragma unroll
    for (int o = 32; o > 0; o >>= 1) sq += __shfl_down(sq, o, 64);
    __syncthreads();
    if ((t & 63) == 0) red[t >> 6] = sq;
    __syncthreads();
    const float var  = (red[0] + red[1] + red[2] + red[3]) * (1.f / 1024.f);
    const float rstd = rsqrtf(var + 1e-5f);

    const int c = t * 4;
    float4 gv = *(const float4*)&g[c];
    float4 bv = *(const float4*)&bta[c];
    float4 o4;
    o4.x = d0 * rstd * gv.x + bv.x;
    o4.y = d1 * rstd * gv.y + bv.y;
    o4.z = d2 * rstd * gv.z + bv.z;
    o4.w = d3 * rstd * gv.w + bv.w;
    *(float4*)&out[base] = o4;
    if (WRITE_BF) {
        ushort4 ob;
        ob.x = f2bf(o4.x); ob.y = f2bf(o4.y); ob.z = f2bf(o4.z); ob.w = f2bf(o4.w);
        *(ushort4*)&out_bf[base] = ob;
    }
}

// ---------------------------------------------------------------------------
extern "C" void kernel_launch(void* const* d_in, const int* in_sizes, int n_in,
                              void* d_out, int out_size, void* d_ws, size_t ws_size,
                              hipStream_t stream)
{
    const float* src = (const float*)d_in[0];
    const float* Wq  = (const float*)d_in[1];  const float* bq = (const float*)d_in[2];
    const float* Wk  = (const float*)d_in[3];  const float* bk = (const float*)d_in[4];
    const float* Wv  = (const float*)d_in[5];  const float* bv = (const float*)d_in[6];
    const float* Wo  = (const float*)d_in[7];  const float* bo = (const float*)d_in[8];
    const float* W1  = (const float*)d_in[9];  const float* b1 = (const float*)d_in[10];
    const float* W2  = (const float*)d_in[11]; const float* b2 = (const float*)d_in[12];
    const float* g1  = (const float*)d_in[13]; const float* be1 = (const float*)d_in[14];
    const float* g2  = (const float*)d_in[15]; const float* be2 = (const float*)d_in[16];
    float* out = (float*)d_out;

    char* ws = (char*)d_ws;
    const size_t MB = 1024 * 1024;
    ushort* Qb    = (ushort*)(ws);              // [0,16M); K at +16M, Vt at +32M
    ushort* Kb    = (ushort*)(ws + 16 * MB);
    ushort* Vtb   = (ushort*)(ws + 32 * MB);
    ushort* CTXb  = (ushort*)(ws + 48 * MB);
    ushort* FFb   = (ushort*)(ws);              // [0,64M) after attn+O-proj
    float*  Xf    = (float*) (ws + 64 * MB);
    ushort* X1b   = (ushort*)(ws + 96 * MB);
    ushort* SRCb  = (ushort*)(ws + 112 * MB);
    ushort* W1t   = (ushort*)(ws + 112 * MB);   // after SRCb dead
    ushort* W2t   = (ushort*)(ws + 120 * MB);
    ushort* Wqkvt = (ushort*)(ws + 128 * MB);   // [3072,1024] bf16, 6 MB
    ushort* Wot   = (ushort*)(ws + 134 * MB);

    dim3 blk(256);

    cast_kernel<<<dim3(M_ROWS * D_MODEL / 1024), blk, 0, stream>>>(src, SRCb);
    transpose_cast4_kernel<<<dim3(16, 16, 4), blk, 0, stream>>>(Wq, Wk, Wv, Wo, Wqkvt, Wot);

    // fused QKV projection -> Qb/Kb/Vtb (bf16; Q scaled 1/8; V transposed)
    gemm_mfma<4><<<dim3(24, 64), blk, 0, stream>>>(
        SRCb, Wqkvt, bq, bk, bv, Qb, M_ROWS, 3 * D_MODEL, D_MODEL, 24);

    transpose_cast_kernel<<<dim3(64, 16), blk, 0, stream>>>(W1, W1t, D_MODEL, D_FF);
    transpose_cast_kernel<<<dim3(16, 64), blk, 0, stream>>>(W2, W2t, D_FF, D_MODEL);

    // flash attention -> CTX bf16
    attn_mfma<<<dim3(SEQ / 128, BATCH * NHEAD), blk, 0, stream>>>(Qb, Kb, Vtb, CTXb);

    // O-projection -> attn_out fp32
    gemm_mfma<0><<<dim3(8, 64), blk, 0, stream>>>(
        CTXb, Wot, bo, nullptr, nullptr, Xf, M_ROWS, D_MODEL, D_MODEL, 8);

    // x1 = LN1(attn_out + src)
    ln_kernel<true><<<M_ROWS, blk, 0, stream>>>(Xf, src, g1, be1, Xf, X1b);

    // FF1 = relu(x1 @ W1 + b1) -> bf16
    gemm_mfma<2><<<dim3(32, 64), blk, 0, stream>>>(
        X1b, W1t, b1, nullptr, nullptr, FFb, M_ROWS, D_FF, D_MODEL, 32);

    // FF2 = FF1 @ W2 + b2 -> fp32 out
    gemm_mfma<0><<<dim3(8, 64), blk, 0, stream>>>(
        FFb, W2t, b2, nullptr, nullptr, out, M_ROWS, D_MODEL, D_FF, 8);

    // out = LN2(FF2 + x1)
    ln_kernel<false><<<M_ROWS, blk, 0, stream>>>(out, Xf, g2, be2, out, nullptr);
}